// Round 3
// baseline (478.449 us; speedup 1.0000x reference)
//
#include <hip/hip_runtime.h>
#include <hip/hip_bf16.h>
#include <math.h>

#define HIDDEN 1024
#define ADIM 32
#define NEMB 32
#define BB 128
#define TT 16
#define NROWS (BB*TT)   // 2048
#define MBMAX 8

typedef float f32x4 __attribute__((ext_vector_type(4)));
typedef short bf16x8 __attribute__((ext_vector_type(8)));
typedef unsigned short u16;

static __device__ __forceinline__ u16 f2bf(float f) {
    union { __hip_bfloat16 h; u16 u; } cv;
    cv.h = __float2bfloat16(f);   // RNE
    return cv.u;
}

// ws layout:
//  [0, 4096)        : meta ints: [0..31]=cnt, [32..63]=off, [64..191]=blist
//  xg  @ 4096       : 2048 x 2048 bf16 (8MB), grouped rows
//  yg  @ +8MB       : 2048 x 1024 bf16 (4MB), grouped rows
//  pbuf @ +4MB      : ksplit x 2048 x 1024 f32 (ksplit*8MB)

__global__ void prep_kernel(const int* __restrict__ cat, int* __restrict__ meta) {
    __shared__ int c[BB];
    int tid = threadIdx.x;
    if (tid < BB) c[tid] = cat[tid];
    __syncthreads();
    if (tid == 0) {
        int cnt[NEMB];
        for (int e = 0; e < NEMB; e++) cnt[e] = 0;
        for (int b = 0; b < BB; b++) cnt[c[b]]++;
        int off = 0;
        for (int e = 0; e < NEMB; e++) { meta[e] = cnt[e]; meta[32 + e] = off; off += cnt[e]; }
        int pos[NEMB];
        for (int e = 0; e < NEMB; e++) pos[e] = meta[32 + e];
        for (int b = 0; b < BB; b++) { int e = c[b]; meta[64 + pos[e]] = b; pos[e]++; }
    }
}

// Layer 1 + PE, written grouped as bf16.
__global__ __launch_bounds__(256) void build_x_kernel(
    const float* __restrict__ actions, const int* __restrict__ timesteps,
    const int* __restrict__ cat_ids, const float* __restrict__ W1,
    const float* __restrict__ b1, const int* __restrict__ meta,
    u16* __restrict__ xg)
{
    int sb = blockIdx.x;
    int b  = meta[64 + sb];
    int e  = cat_ids[b];
    int tid = threadIdx.x;

    __shared__ float act[TT][ADIM];
    for (int i = tid; i < TT * ADIM; i += 256)
        act[i / ADIM][i % ADIM] = actions[(size_t)b * TT * ADIM + i];
    __syncthreads();

    float tau = (float)timesteps[b];

    for (int h = tid; h < HIDDEN; h += 256) {
        float acc[TT];
        #pragma unroll
        for (int t = 0; t < TT; t++) acc[t] = 0.f;
        for (int d = 0; d < ADIM; d++) {
            float w = W1[((size_t)e * ADIM + d) * HIDDEN + h];
            #pragma unroll
            for (int t = 0; t < TT; t++) acc[t] += act[t][d] * w;
        }
        float bv = b1[(size_t)e * HIDDEN + h];
        for (int t = 0; t < TT; t++)
            xg[(size_t)(sb * TT + t) * 2048 + h] = f2bf(acc[t] + bv);
    }

    for (int j = tid; j < HIDDEN; j += 256) {
        int i = j >> 1;
        float arg = tau * expf((float)i * -0.017988946f);
        float v = (j & 1) ? cosf(arg) : sinf(arg);
        u16 bv = f2bf(v);
        for (int t = 0; t < TT; t++)
            xg[(size_t)(sb * TT + t) * 2048 + 1024 + j] = bv;
    }
}

// Streaming grouped GEMM with split-K partials.
// block = 512 thr (8 waves, 2m x 4n), tile: 64m x 512n x 32k per stage.
// B reads: per wave-instr 1KB contiguous; block covers 2KB/row of 32 rows/tile.
// LDS (36KB, single-buffered): subtiled k-octet layout, all 16B-aligned.
__global__ __launch_bounds__(512, 2) void gemm_stream(
    const u16* __restrict__ X,        // grouped rows, bf16, ld = ldx
    const float* __restrict__ W,      // (NEMB, Kdim, 1024) f32
    float* __restrict__ pbuf,         // ksplit x 2048 x 1024 f32
    const int* __restrict__ meta,
    int Kdim, int ldx, int ksplit)
{
    int e     = blockIdx.z / ksplit;
    int kcIdx = blockIdx.z % ksplit;
    int cnt = meta[e];
    int Me  = cnt * TT;
    int mb  = blockIdx.y;
    if (mb * 64 >= Me) return;
    int row0 = meta[32 + e] * TT + mb * 64;
    int rowsValid = Me - mb * 64; if (rowsValid > 64) rowsValid = 64;
    int n0 = blockIdx.x * 512;
    int KC  = Kdim / ksplit;
    int kc0 = kcIdx * KC;
    int nT  = KC / 32;

    // A: 64m x 32k bf16; idx(u16) = (m>>4)*512 + oct*128 + ((m&15)^(m>>4))*8 + (k&7)
    // B: 512n x 32k bf16; idx(u16) = (n>>4)*512 + oct*128 + ((n&15)^((n>>4)&15))*8 + (k&7)
    __shared__ u16 As[4 * 512];        // 4KB
    __shared__ u16 Bs[32 * 512];       // 32KB

    int tid  = threadIdx.x;
    int lane = tid & 63;
    int wid  = tid >> 6;
    int wm   = wid & 1;     // 2 m-halves (32 rows each)
    int wn   = wid >> 1;    // 4 n-slices (128 cols each)

    const float* Wp = W + (size_t)e * Kdim * 1024 + n0;

    // B stage: thread -> (n-quad bn4 0..127, k-octet bkr 0..3), 8 rows each
    int bn4 = tid & 127;
    int bkr = tid >> 7;
    // A stage: threads 0..255 -> (m = t>>2, k-octet = t&3)
    int am   = tid >> 2;
    int aoct = tid & 3;

    f32x4 bReg[8];
    bf16x8 aReg;

    f32x4 acc[2][8];
    #pragma unroll
    for (int mi = 0; mi < 2; mi++)
        #pragma unroll
        for (int g = 0; g < 8; g++)
            acc[mi][g] = (f32x4){0.f, 0.f, 0.f, 0.f};

    auto loadB = [&](int kt) {
        int kbase = kc0 + kt * 32 + bkr * 8;
        #pragma unroll
        for (int r = 0; r < 8; r++)
            bReg[r] = *(const f32x4*)&Wp[(size_t)(kbase + r) * 1024 + bn4 * 4];
    };
    auto loadA = [&](int kt) {
        if (tid < 256)
            aReg = *(const bf16x8*)&X[(size_t)(row0 + am) * ldx + kc0 + kt * 32 + aoct * 8];
    };
    auto writeB = [&]() {
        #pragma unroll
        for (int j = 0; j < 4; j++) {
            int n = bn4 * 4 + j;
            bf16x8 v;
            #pragma unroll
            for (int r = 0; r < 8; r++) v[r] = (short)f2bf(bReg[r][j]);
            int idx = (n >> 4) * 512 + bkr * 128 + (((n & 15) ^ ((n >> 4) & 15)) << 3);
            *(bf16x8*)&Bs[idx] = v;
        }
    };
    auto writeA = [&]() {
        if (tid < 256) {
            int idx = (am >> 4) * 512 + aoct * 128 + (((am & 15) ^ (am >> 4)) << 3);
            *(bf16x8*)&As[idx] = aReg;
        }
    };
    auto compute = [&]() {
        int octr = lane >> 4;
        int lf   = lane & 15;
        bf16x8 af[2];
        #pragma unroll
        for (int mi = 0; mi < 2; mi++) {
            int gm = wm * 2 + mi;                 // m16-group 0..3
            af[mi] = *(const bf16x8*)&As[gm * 512 + octr * 128 + ((lf ^ gm) << 3)];
        }
        #pragma unroll
        for (int g = 0; g < 8; g++) {
            int gn = wn * 8 + g;                  // n16-group 0..31
            bf16x8 bf = *(const bf16x8*)&Bs[gn * 512 + octr * 128 + ((lf ^ (gn & 15)) << 3)];
            #pragma unroll
            for (int mi = 0; mi < 2; mi++)
                acc[mi][g] = __builtin_amdgcn_mfma_f32_16x16x32_bf16(af[mi], bf, acc[mi][g], 0, 0, 0);
        }
    };

    loadB(0); loadA(0);
    for (int kt = 0; kt < nT; kt++) {
        writeB(); writeA();                       // drains loads(kt)
        if (kt + 1 < nT) { loadB(kt + 1); loadA(kt + 1); }  // in flight across compute
        __syncthreads();
        compute();
        __syncthreads();
    }

    // partial C store
    float* pb = pbuf + (size_t)kcIdx * NROWS * 1024;
    int colbase = n0 + wn * 128 + (lane & 15);
    int rowb = wm * 32 + ((lane >> 4) << 2);
    #pragma unroll
    for (int mi = 0; mi < 2; mi++) {
        #pragma unroll
        for (int r = 0; r < 4; r++) {
            int m = rowb + mi * 16 + r;
            if (m < rowsValid) {
                float* dst = pb + (size_t)(row0 + m) * 1024 + colbase;
                #pragma unroll
                for (int g = 0; g < 8; g++)
                    dst[g * 16] = acc[mi][g][r];
            }
        }
    }
}

// yg = bf16(swish(sum_kc pbuf + b2)), grouped rows
__global__ __launch_bounds__(256) void reduce_mid(
    const float* __restrict__ pbuf, const float* __restrict__ b2,
    const int* __restrict__ meta, const int* __restrict__ cat,
    u16* __restrict__ yg, int ksplit)
{
    int r = blockIdx.x;
    int e = cat[meta[64 + (r >> 4)]];
    int c = threadIdx.x * 4;
    f32x4 s = *(const f32x4*)&pbuf[(size_t)r * 1024 + c];
    for (int kc = 1; kc < ksplit; kc++) {
        f32x4 t = *(const f32x4*)&pbuf[(size_t)kc * NROWS * 1024 + (size_t)r * 1024 + c];
        s = s + t;
    }
    f32x4 bb = *(const f32x4*)&b2[(size_t)e * 1024 + c];
    ushort4 o;
    float h0 = s[0] + bb[0]; o.x = f2bf(h0 / (1.f + expf(-h0)));
    float h1 = s[1] + bb[1]; o.y = f2bf(h1 / (1.f + expf(-h1)));
    float h2 = s[2] + bb[2]; o.z = f2bf(h2 / (1.f + expf(-h2)));
    float h3 = s[3] + bb[3]; o.w = f2bf(h3 / (1.f + expf(-h3)));
    *(ushort4*)&yg[(size_t)r * 1024 + c] = o;
}

// out[natural] = sum_kc pbuf + b3
__global__ __launch_bounds__(256) void reduce_out(
    const float* __restrict__ pbuf, const float* __restrict__ b3,
    const int* __restrict__ meta, const int* __restrict__ cat,
    float* __restrict__ out, int ksplit)
{
    int r = blockIdx.x;
    int sb = r >> 4;
    int bnat = meta[64 + sb];
    int e = cat[bnat];
    int c = threadIdx.x * 4;
    f32x4 s = *(const f32x4*)&pbuf[(size_t)r * 1024 + c];
    for (int kc = 1; kc < ksplit; kc++) {
        f32x4 t = *(const f32x4*)&pbuf[(size_t)kc * NROWS * 1024 + (size_t)r * 1024 + c];
        s = s + t;
    }
    f32x4 bb = *(const f32x4*)&b3[(size_t)e * 1024 + c];
    s = s + bb;
    *(f32x4*)&out[((size_t)bnat * TT + (r & 15)) * 1024 + c] = s;
}

extern "C" void kernel_launch(void* const* d_in, const int* in_sizes, int n_in,
                              void* d_out, int out_size, void* d_ws, size_t ws_size,
                              hipStream_t stream) {
    const float* actions   = (const float*)d_in[0];
    const int*   timesteps = (const int*)d_in[1];
    const int*   cat_ids   = (const int*)d_in[2];
    const float* W1        = (const float*)d_in[3];
    const float* b1        = (const float*)d_in[4];
    const float* W2        = (const float*)d_in[5];
    const float* b2        = (const float*)d_in[6];
    const float* W3        = (const float*)d_in[7];
    const float* b3        = (const float*)d_in[8];
    float* out = (float*)d_out;

    int*  meta = (int*)d_ws;
    u16*  xg   = (u16*)((char*)d_ws + 4096);
    u16*  yg   = (u16*)((char*)d_ws + 4096 + 8ull * 1024 * 1024);
    float* pbuf = (float*)((char*)d_ws + 4096 + 12ull * 1024 * 1024);

    // pick split-K from available workspace (deterministic in ws_size)
    size_t fixed = 4096 + 12ull * 1024 * 1024;
    size_t avail = ws_size > fixed ? ws_size - fixed : 0;
    const size_t PB = (size_t)NROWS * 1024 * 4;   // 8MB per split
    int ksplit = 1;
    if      (avail >= 8 * PB) ksplit = 8;
    else if (avail >= 4 * PB) ksplit = 4;
    else if (avail >= 2 * PB) ksplit = 2;

    prep_kernel<<<1, 128, 0, stream>>>(cat_ids, meta);
    build_x_kernel<<<128, 256, 0, stream>>>(actions, timesteps, cat_ids, W1, b1, meta, xg);

    // layer 2: K=2048
    gemm_stream<<<dim3(2, MBMAX, NEMB * ksplit), 512, 0, stream>>>(
        xg, W2, pbuf, meta, 2048, 2048, ksplit);
    reduce_mid<<<NROWS, 256, 0, stream>>>(pbuf, b2, meta, cat_ids, yg, ksplit);

    // layer 3: K=1024
    gemm_stream<<<dim3(2, MBMAX, NEMB * ksplit), 512, 0, stream>>>(
        yg, W3, pbuf, meta, 1024, 1024, ksplit);
    reduce_out<<<NROWS, 256, 0, stream>>>(pbuf, b3, meta, cat_ids, out, ksplit);
}

// Round 4
// 208.811 us; speedup vs baseline: 2.2913x; 2.2913x over previous
//
#include <hip/hip_runtime.h>
#include <hip/hip_bf16.h>
#include <math.h>

#define HIDDEN 1024
#define ADIM 32
#define NEMB 32
#define BB 128
#define TT 16
#define NROWS (BB*TT)   // 2048
#define KSPLIT 4

#define OCT_STRIDE 136    // u16: 128 data + 8 pad (bank +4 rotation per octet)
#define GN_STRIDE  1096   // u16: 8*136 + 8 pad (bank +4 rotation per n16-group)
#define BS_U16     (16 * GN_STRIDE)   // 17536 u16 = 35072 B per buffer

typedef float f32x4 __attribute__((ext_vector_type(4)));
typedef short bf16x8 __attribute__((ext_vector_type(8)));
typedef unsigned short u16;

static __device__ __forceinline__ u16 f2bf(float f) {
    union { __hip_bfloat16 h; u16 u; } cv;
    cv.h = __float2bfloat16(f);   // RNE
    return cv.u;
}

// ws layout:
//  [0, 4096)   : meta ints: [0..31]=cnt, [32..63]=off, [64..191]=blist,
//                [192]=ntiles, [200+4i..]=tiles (row0, rows, e)
//  xg  @ 4096  : 2048 x 2048 bf16 (8MB), grouped rows
//  yg  @ +8MB  : 2048 x 1024 bf16 (4MB), grouped rows
//  pbuf @ +4MB : KSPLIT x 2048 x 1024 f32 (32MB)

__global__ void prep_kernel(const int* __restrict__ cat, int* __restrict__ meta) {
    __shared__ int c[BB];
    int tid = threadIdx.x;
    if (tid < BB) c[tid] = cat[tid];
    __syncthreads();
    if (tid == 0) {
        int cnt[NEMB];
        for (int e = 0; e < NEMB; e++) cnt[e] = 0;
        for (int b = 0; b < BB; b++) cnt[c[b]]++;
        int off = 0;
        for (int e = 0; e < NEMB; e++) { meta[e] = cnt[e]; meta[32 + e] = off; off += cnt[e]; }
        int pos[NEMB];
        for (int e = 0; e < NEMB; e++) pos[e] = meta[32 + e];
        for (int b = 0; b < BB; b++) { int e = c[b]; meta[64 + pos[e]] = b; pos[e]++; }
        // tile worklist: 64-row tiles within each embedding's grouped segment
        int nt = 0;
        for (int e = 0; e < NEMB; e++) {
            int Me = cnt[e] * TT;
            int base = meta[32 + e] * TT;
            for (int mb = 0; mb * 64 < Me; mb++) {
                int rows = Me - mb * 64; if (rows > 64) rows = 64;
                meta[200 + 4 * nt + 0] = base + mb * 64;
                meta[200 + 4 * nt + 1] = rows;
                meta[200 + 4 * nt + 2] = e;
                nt++;
            }
        }
        meta[192] = nt;   // <= 56
    }
}

// Layer 1 + PE, written grouped as bf16.
__global__ __launch_bounds__(256) void build_x_kernel(
    const float* __restrict__ actions, const int* __restrict__ timesteps,
    const int* __restrict__ cat_ids, const float* __restrict__ W1,
    const float* __restrict__ b1, const int* __restrict__ meta,
    u16* __restrict__ xg)
{
    int sb = blockIdx.x;
    int b  = meta[64 + sb];
    int e  = cat_ids[b];
    int tid = threadIdx.x;

    __shared__ float act[TT][ADIM];
    for (int i = tid; i < TT * ADIM; i += 256)
        act[i / ADIM][i % ADIM] = actions[(size_t)b * TT * ADIM + i];
    __syncthreads();

    float tau = (float)timesteps[b];

    for (int h = tid; h < HIDDEN; h += 256) {
        float acc[TT];
        #pragma unroll
        for (int t = 0; t < TT; t++) acc[t] = 0.f;
        for (int d = 0; d < ADIM; d++) {
            float w = W1[((size_t)e * ADIM + d) * HIDDEN + h];
            #pragma unroll
            for (int t = 0; t < TT; t++) acc[t] += act[t][d] * w;
        }
        float bv = b1[(size_t)e * HIDDEN + h];
        for (int t = 0; t < TT; t++)
            xg[(size_t)(sb * TT + t) * 2048 + h] = f2bf(acc[t] + bv);
    }

    for (int j = tid; j < HIDDEN; j += 256) {
        int i = j >> 1;
        float arg = tau * expf((float)i * -0.017988946f);
        float v = (j & 1) ? cosf(arg) : sinf(arg);
        u16 bv = f2bf(v);
        for (int t = 0; t < TT; t++)
            xg[(size_t)(sb * TT + t) * 2048 + 1024 + j] = bv;
    }
}

// Streaming grouped GEMM, split-K partials.
// 1D grid: bid = kc + 4*nq + 16*slot  (work in LOW bits -> uniform XCD/CU spread,
// dead blocks form one contiguous tail). Tile 64m x 256n, BK=64, dbuf LDS,
// 1 barrier/K-step, B reg-prefetched 1 step ahead, A direct from global bf16.
__global__ __launch_bounds__(512, 4) void gemm_stream(
    const u16* __restrict__ X,        // grouped rows bf16, ld = ldx
    const float* __restrict__ W,      // (NEMB, Kdim, 1024) f32
    float* __restrict__ pbuf,         // KSPLIT x 2048 x 1024 f32
    const int* __restrict__ meta,
    int Kdim, int ldx)
{
    int bid  = blockIdx.x;
    int kc   = bid & 3;
    int nq   = (bid >> 2) & 3;
    int slot = bid >> 4;
    if (slot >= meta[192]) return;
    int row0      = meta[200 + 4 * slot + 0];
    int rowsValid = meta[200 + 4 * slot + 1];
    int e         = meta[200 + 4 * slot + 2];

    int n0  = nq * 256;
    int KC  = Kdim / KSPLIT;
    int kc0 = kc * KC;
    int nT  = KC >> 6;          // K-steps of 64

    __shared__ u16 Bs[2][BS_U16];

    int tid  = threadIdx.x;
    int lane = tid & 63;
    int wid  = tid >> 6;
    int wm   = wid & 1;     // m-half (32 rows)
    int wn   = wid >> 1;    // n-quarter (64 cols = 4 gn)

    const float* Wp = W + (size_t)e * Kdim * 1024 + n0;

    // B stage map: bn4 = n-quad (0..63), bo = k-octet (0..7); 8 rows f32x4 each.
    int bn4 = tid & 63;
    int bo  = tid >> 6;

    f32x4 bReg[8];
    f32x4 acc[2][4];
    #pragma unroll
    for (int mi = 0; mi < 2; mi++)
        #pragma unroll
        for (int g = 0; g < 4; g++)
            acc[mi][g] = (f32x4){0.f, 0.f, 0.f, 0.f};

    auto loadB = [&](int kt) {
        int kb = kc0 + kt * 64 + bo * 8;
        #pragma unroll
        for (int r = 0; r < 8; r++)
            bReg[r] = *(const f32x4*)&Wp[(size_t)(kb + r) * 1024 + bn4 * 4];
    };
    auto writeB = [&](int c) {
        #pragma unroll
        for (int j = 0; j < 4; j++) {
            int n = bn4 * 4 + j;
            bf16x8 v;
            #pragma unroll
            for (int r = 0; r < 8; r++) v[r] = (short)f2bf(bReg[r][j]);
            *(bf16x8*)&Bs[c][(n >> 4) * GN_STRIDE + bo * OCT_STRIDE + (n & 15) * 8] = v;
        }
    };
    auto compute = [&](int c, int kt) {
        int kg = kc0 + kt * 64;
        #pragma unroll
        for (int h = 0; h < 2; h++) {
            bf16x8 af[2];
            #pragma unroll
            for (int mi = 0; mi < 2; mi++) {
                int m = wm * 32 + mi * 16 + (lane & 15);
                af[mi] = *(const bf16x8*)&X[(size_t)(row0 + m) * ldx + kg + h * 32 + (lane >> 4) * 8];
            }
            #pragma unroll
            for (int g = 0; g < 4; g++) {
                int gn = wn * 4 + g;
                bf16x8 bf = *(const bf16x8*)&Bs[c][gn * GN_STRIDE + (h * 4 + (lane >> 4)) * OCT_STRIDE + (lane & 15) * 8];
                #pragma unroll
                for (int mi = 0; mi < 2; mi++)
                    acc[mi][g] = __builtin_amdgcn_mfma_f32_16x16x32_bf16(af[mi], bf, acc[mi][g], 0, 0, 0);
            }
        }
    };

    loadB(0);
    for (int kt = 0; kt < nT; kt++) {
        writeB(kt & 1);                    // vmcnt-drains loads(kt)
        if (kt + 1 < nT) loadB(kt + 1);    // in flight across barrier+compute
        __syncthreads();                   // single barrier per step (dbuf-safe)
        compute(kt & 1, kt);
    }

    // partial store (row-major pbuf)
    float* pb = pbuf + (size_t)kc * NROWS * 1024;
    int col = n0 + wn * 64 + (lane & 15);
    #pragma unroll
    for (int mi = 0; mi < 2; mi++) {
        #pragma unroll
        for (int r = 0; r < 4; r++) {
            int m = wm * 32 + mi * 16 + ((lane >> 4) << 2) + r;
            if (m < rowsValid) {
                float* dst = pb + (size_t)(row0 + m) * 1024 + col;
                #pragma unroll
                for (int g = 0; g < 4; g++)
                    dst[g * 16] = acc[mi][g][r];
            }
        }
    }
}

// yg = bf16(swish(sum_kc pbuf + b2)), grouped rows
__global__ __launch_bounds__(256) void reduce_mid(
    const float* __restrict__ pbuf, const float* __restrict__ b2,
    const int* __restrict__ meta, const int* __restrict__ cat,
    u16* __restrict__ yg)
{
    int r = blockIdx.x;
    int e = cat[meta[64 + (r >> 4)]];
    int c = threadIdx.x * 4;
    f32x4 s = *(const f32x4*)&pbuf[(size_t)r * 1024 + c];
    #pragma unroll
    for (int kc = 1; kc < KSPLIT; kc++) {
        f32x4 t = *(const f32x4*)&pbuf[(size_t)kc * NROWS * 1024 + (size_t)r * 1024 + c];
        s = s + t;
    }
    f32x4 bb = *(const f32x4*)&b2[(size_t)e * 1024 + c];
    ushort4 o;
    float h0 = s[0] + bb[0]; o.x = f2bf(h0 / (1.f + expf(-h0)));
    float h1 = s[1] + bb[1]; o.y = f2bf(h1 / (1.f + expf(-h1)));
    float h2 = s[2] + bb[2]; o.z = f2bf(h2 / (1.f + expf(-h2)));
    float h3 = s[3] + bb[3]; o.w = f2bf(h3 / (1.f + expf(-h3)));
    *(ushort4*)&yg[(size_t)r * 1024 + c] = o;
}

// out[natural] = sum_kc pbuf + b3
__global__ __launch_bounds__(256) void reduce_out(
    const float* __restrict__ pbuf, const float* __restrict__ b3,
    const int* __restrict__ meta, const int* __restrict__ cat,
    float* __restrict__ out)
{
    int r = blockIdx.x;
    int bnat = meta[64 + (r >> 4)];
    int e = cat[bnat];
    int c = threadIdx.x * 4;
    f32x4 s = *(const f32x4*)&pbuf[(size_t)r * 1024 + c];
    #pragma unroll
    for (int kc = 1; kc < KSPLIT; kc++) {
        f32x4 t = *(const f32x4*)&pbuf[(size_t)kc * NROWS * 1024 + (size_t)r * 1024 + c];
        s = s + t;
    }
    f32x4 bb = *(const f32x4*)&b3[(size_t)e * 1024 + c];
    s = s + bb;
    *(f32x4*)&out[((size_t)bnat * TT + (r & 15)) * 1024 + c] = s;
}

extern "C" void kernel_launch(void* const* d_in, const int* in_sizes, int n_in,
                              void* d_out, int out_size, void* d_ws, size_t ws_size,
                              hipStream_t stream) {
    const float* actions   = (const float*)d_in[0];
    const int*   timesteps = (const int*)d_in[1];
    const int*   cat_ids   = (const int*)d_in[2];
    const float* W1        = (const float*)d_in[3];
    const float* b1        = (const float*)d_in[4];
    const float* W2        = (const float*)d_in[5];
    const float* b2        = (const float*)d_in[6];
    const float* W3        = (const float*)d_in[7];
    const float* b3        = (const float*)d_in[8];
    float* out = (float*)d_out;

    int*  meta  = (int*)d_ws;
    u16*  xg    = (u16*)((char*)d_ws + 4096);
    u16*  yg    = (u16*)((char*)d_ws + 4096 + 8ull * 1024 * 1024);
    float* pbuf = (float*)((char*)d_ws + 4096 + 12ull * 1024 * 1024);

    prep_kernel<<<1, 128, 0, stream>>>(cat_ids, meta);
    build_x_kernel<<<128, 256, 0, stream>>>(actions, timesteps, cat_ids, W1, b1, meta, xg);

    // layer 2: K=2048 (grid: 16 * 64 tile slots; dead tail exits on meta read)
    gemm_stream<<<1024, 512, 0, stream>>>(xg, W2, pbuf, meta, 2048, 2048);
    reduce_mid<<<NROWS, 256, 0, stream>>>(pbuf, b2, meta, cat_ids, yg);

    // layer 3: K=1024
    gemm_stream<<<1024, 512, 0, stream>>>(yg, W3, pbuf, meta, 1024, 1024);
    reduce_out<<<NROWS, 256, 0, stream>>>(pbuf, b3, meta, cat_ids, out);
}